// Round 11
// baseline (193.078 us; speedup 1.0000x reference)
//
#include <hip/hip_runtime.h>

#define NREL 32

typedef short short8 __attribute__((ext_vector_type(8)));
typedef float f32x4 __attribute__((ext_vector_type(4)));

__device__ inline unsigned short f2bf(float f) {
    union { float f; unsigned u; } u; u.f = f;
    unsigned r = u.u + 0x7FFF + ((u.u >> 16) & 1);   // RNE
    return (unsigned short)(r >> 16);
}

// ---------------------------------------------------------------------------
// ws layout:
//   wtb  [2*32*4096] ushort  bf16 normalized tables, TRANSPOSED
//   xbf  [N*64] ushort       bf16(x)
//   cntf [N] int | cntb [N] int | fill [32] int   (zeroed by memset)
//   curS [N] int             CSR cursors keyed by SRC  (gathers msgB)
//   curD [N] int             CSR cursors keyed by DST  (gathers msgF)
//   invF [N] f32             1/(cntf+1)  (fwd degree, src-based)
//   invB [N] f32             1/(cntb+1)  (bwd degree, dst-based)
//   csrS [E] int             edge ids grouped by src-node
//   csrD [E] int             edge ids grouped by dst-node
//   einfo[32*CAP] int4       {src, dst, e, 0} fixed-capacity rel buckets
//   msgF [E*64] f32 | msgB [E*64] f32   per-edge messages (scaled by 1/deg)
// ---------------------------------------------------------------------------

__global__ __launch_bounds__(256) void setup_kernel(
        const float* __restrict__ x,
        const int* __restrict__ src, const int* __restrict__ dst,
        const int* __restrict__ et,
        const float* __restrict__ wf, const float* __restrict__ wb,
        const float* __restrict__ lw, const float* __restrict__ lb,
        int* __restrict__ cntf, int* __restrict__ cntb,
        int* __restrict__ fill, unsigned short* __restrict__ wtb,
        unsigned short* __restrict__ xbf, int4* __restrict__ einfo,
        float* __restrict__ out, int E, int N, int nCountB, int CAP) {
    __shared__ float smem[4 * 8 * 64 + 8];
    int tid = threadIdx.x;
    int b = blockIdx.x;

    if (b < nCountB) {
        // ---- count + scatter role (block-aggregated cursors) ----
        int* lh = (int*)smem;          // [0..31] per-rel block count
        int* lbase = lh + NREL;        // [32..63] reserved global base
        if (tid < 2 * NREL) lh[tid] = 0;
        __syncthreads();
        int e = b * 256 + tid;
        int s = 0, d = 0, r = 0, my = 0;
        bool valid = (e < E);
        if (valid) {
            s = src[e]; d = dst[e]; r = et[e];
            atomicAdd(&cntf[s], 1);
            atomicAdd(&cntb[d], 1);
            my = atomicAdd(&lh[r], 1);
        }
        __syncthreads();
        if (tid < NREL && lh[tid]) lbase[tid] = atomicAdd(&fill[tid], lh[tid]);
        __syncthreads();
        if (valid) einfo[r * CAP + lbase[r] + my] = make_int4(s, d, e, 0);
        return;
    }
    b -= nCountB;
    if (b < 64) {
        // ---- norm role: normalize fp32 table row, write bf16 transposed ----
        int rel = b & 31, tab = b >> 5;
        const float* s_ = (tab ? wb : wf) + rel * 4096;
        unsigned short* d_ = wtb + (size_t)b * 4096;
        float* part = smem;
        float ssum = 0.f;
        #pragma unroll
        for (int k = 0; k < 16; k += 4) {
            float4 v = *(const float4*)(s_ + tid * 16 + k);
            ssum += v.x * v.x + v.y * v.y + v.z * v.z + v.w * v.w;
        }
        #pragma unroll
        for (int off = 32; off >= 1; off >>= 1) ssum += __shfl_down(ssum, off, 64);
        if ((tid & 63) == 0) part[tid >> 6] = ssum;
        __syncthreads();
        if (tid == 0) part[4] = 1.0f / (sqrtf(part[0] + part[1] + part[2] + part[3]) + 0.01f);
        __syncthreads();
        float sc = part[4];
        int i = tid >> 2, o0 = (tid & 3) * 16;
        #pragma unroll
        for (int q = 0; q < 4; ++q) {
            float4 v = *(const float4*)(s_ + i * 64 + o0 + q * 4);
            d_[(o0 + q * 4 + 0) * 64 + i] = f2bf(v.x * sc);
            d_[(o0 + q * 4 + 1) * 64 + i] = f2bf(v.y * sc);
            d_[(o0 + q * 4 + 2) * 64 + i] = f2bf(v.z * sc);
            d_[(o0 + q * 4 + 3) * 64 + i] = f2bf(v.w * sc);
        }
        return;
    }
    b -= 64;
    // ---- linear + xbf role: 32 nodes/block ----
    {
        int lane = tid & 63, w = tid >> 6;
        int nodeBase = b * 32 + w * 8;
        float4 wrow[16];
        const float4* lwrow = (const float4*)(lw + lane * 64);
        #pragma unroll
        for (int g = 0; g < 16; ++g) wrow[g] = lwrow[g];
        float bias = lb[lane];
        float* xs = smem + w * 8 * 64;
        #pragma unroll
        for (int t = 0; t < 8; ++t) {
            int n = nodeBase + t;
            if (n < N) {
                float v = x[(size_t)n * 64 + lane];
                xs[t * 64 + lane] = v;
                xbf[(size_t)n * 64 + lane] = f2bf(v);
            }
        }
        __syncthreads();
        for (int t = 0; t < 8; ++t) {
            int n = nodeBase + t;
            if (n >= N) break;
            float acc = bias;
            const float4* xr = (const float4*)(xs + t * 64);
            #pragma unroll
            for (int g = 0; g < 16; ++g) {
                float4 xv = xr[g];
                acc = fmaf(xv.x, wrow[g].x, acc);
                acc = fmaf(xv.y, wrow[g].y, acc);
                acc = fmaf(xv.z, wrow[g].z, acc);
                acc = fmaf(xv.w, wrow[g].w, acc);
            }
            out[(size_t)n * 64 + lane] = acc;
        }
    }
}

// One block, 1024 threads: exclusive scans of cntf/cntb -> CSR start cursors.
// pass 0: cntf -> curS (src-keyed CSR, gathers msgB) + invF = 1/(cntf+1)
// pass 1: cntb -> curD (dst-keyed CSR, gathers msgF) + invB = 1/(cntb+1)
__global__ __launch_bounds__(1024) void offsets_kernel(
        const int* __restrict__ cntf, const int* __restrict__ cntb,
        int* __restrict__ curS, int* __restrict__ curD,
        float* __restrict__ invF, float* __restrict__ invB, int N) {
    __shared__ int wsum[16];
    __shared__ int wexcl[16];
    int tid = threadIdx.x, lane = tid & 63, wv = tid >> 6;
    int per = (N + 1023) >> 10;
    for (int pass = 0; pass < 2; ++pass) {
        const int* c = pass ? cntb : cntf;
        int* cur = pass ? curD : curS;
        float* ivd = pass ? invB : invF;
        int base = tid * per;
        int sum = 0;
        for (int i = 0; i < per; ++i) { int n = base + i; if (n < N) sum += c[n]; }
        int v = sum;
        #pragma unroll
        for (int off = 1; off < 64; off <<= 1) {
            int t = __shfl_up(v, off, 64);
            if (lane >= off) v += t;
        }
        if (lane == 63) wsum[wv] = v;
        __syncthreads();
        if (tid == 0) { int a = 0; for (int q = 0; q < 16; ++q) { wexcl[q] = a; a += wsum[q]; } }
        __syncthreads();
        int run = wexcl[wv] + (v - sum);
        for (int i = 0; i < per; ++i) {
            int n = base + i;
            if (n < N) {
                int cn = c[n];
                cur[n] = run;
                ivd[n] = 1.0f / (float)(cn + 1);
                run += cn;
            }
        }
        __syncthreads();   // protect wsum/wexcl reuse in pass 2
    }
}

// csrS grouped by src[e] (bwd messages land at src); csrD grouped by dst[e]
// (fwd messages land at dst).
__global__ void csrfill_kernel(const int* __restrict__ src, const int* __restrict__ dst,
                               int* __restrict__ curS, int* __restrict__ curD,
                               int* __restrict__ csrS, int* __restrict__ csrD, int E) {
    int e = blockIdx.x * 256 + threadIdx.x;
    if (e >= E) return;
    int pS = atomicAdd(&curS[src[e]], 1); csrS[pS] = e;
    int pD = atomicAdd(&curD[dst[e]], 1); csrD[pD] = e;
}

// One block per 64-edge chunk, both directions. Epilogue: PLAIN stores of the
// scaled per-edge messages to msgF/msgB (no atomics).
#define APITCH 72  // 64 + 8 shorts pad
__global__ __launch_bounds__(256) void conv_mfma(
        const unsigned short* __restrict__ xbf,
        const float* __restrict__ invF, const float* __restrict__ invB,
        const int* __restrict__ fill,
        const unsigned short* __restrict__ wtb,
        const int4* __restrict__ einfo,
        float* __restrict__ msgF, float* __restrict__ msgB, int CAP) {
    int tid = threadIdx.x;
    int lane = tid & 63;

    // 64-edge chunk-count scan over fill[32]
    int fr = (lane < NREL) ? fill[lane] : 0;
    int ch = (fr + 63) >> 6;
    int s_scan = ch;
    #pragma unroll
    for (int off = 1; off < 32; off <<= 1) {
        int t = __shfl_up(s_scan, off, 64);
        if ((lane & 31) >= off) s_scan += t;
    }
    int chExcl = s_scan - ch;

    int c = blockIdx.x;
    unsigned long long mm = __ballot(lane < NREL && c >= chExcl && c < chExcl + ch);
    if (mm == 0) return;
    int rel = __ffsll(mm) - 1;
    int lc = c - __shfl(chExcl, rel, 64);
    int frr = __shfl(fr, rel, 64);
    int pos = rel * CAP + lc * 64;
    int valid = frr - lc * 64;
    if (valid > 64) valid = 64;

    __shared__ unsigned short Af[64 * APITCH];
    __shared__ unsigned short Ab[64 * APITCH];
    __shared__ unsigned short Bf[64 * APITCH];
    __shared__ unsigned short Bb[64 * APITCH];
    __shared__ int eS[64];
    __shared__ float ivF[64], ivB[64];

    int j = tid >> 2, part = tid & 3;

    // stage B: both tables
    {
        size_t off = (size_t)rel * 4096 + j * 64 + part * 16;
        const uint4* sf = (const uint4*)(wtb + off);
        const uint4* sb = (const uint4*)(wtb + (size_t)NREL * 4096 + off);
        uint4 f0 = sf[0], f1 = sf[1], b0 = sb[0], b1 = sb[1];
        *(uint4*)(&Bf[j * APITCH + part * 16]) = f0;
        *(uint4*)(&Bf[j * APITCH + part * 16 + 8]) = f1;
        *(uint4*)(&Bb[j * APITCH + part * 16]) = b0;
        *(uint4*)(&Bb[j * APITCH + part * 16 + 8]) = b1;
    }

    // stage A
    if (j >= valid) {
        uint4 z = {0, 0, 0, 0};
        *(uint4*)(&Af[j * APITCH + part * 16]) = z;
        *(uint4*)(&Af[j * APITCH + part * 16 + 8]) = z;
        *(uint4*)(&Ab[j * APITCH + part * 16]) = z;
        *(uint4*)(&Ab[j * APITCH + part * 16 + 8]) = z;
        if (part == 0) { eS[j] = -1; ivF[j] = 0.f; ivB[j] = 0.f; }
    } else {
        int4 v = einfo[pos + j];                 // {src, dst, e, 0}
        const uint4* xs = (const uint4*)(xbf + (size_t)v.x * 64);
        const uint4* xd = (const uint4*)(xbf + (size_t)v.y * 64);
        uint4 s0 = xs[part * 2], s1 = xs[part * 2 + 1];
        uint4 d0 = xd[part * 2], d1 = xd[part * 2 + 1];
        *(uint4*)(&Af[j * APITCH + part * 16]) = s0;
        *(uint4*)(&Af[j * APITCH + part * 16 + 8]) = s1;
        *(uint4*)(&Ab[j * APITCH + part * 16]) = d0;
        *(uint4*)(&Ab[j * APITCH + part * 16 + 8]) = d1;
        if (part == 0) {
            eS[j] = v.z;
            ivF[j] = invF[v.x];    // fwd degree: src-based
            ivB[j] = invB[v.y];    // bwd degree: dst-based
        }
    }
    __syncthreads();

    // MFMA: wave w computes edge rows [16w,16w+16) x 64 channels, both dirs
    int w = tid >> 6;
    int m = lane & 15, quad = lane >> 4;
    f32x4 zero4 = {0.f, 0.f, 0.f, 0.f};
    f32x4 accF[4] = {zero4, zero4, zero4, zero4};
    f32x4 accB[4] = {zero4, zero4, zero4, zero4};
    #pragma unroll
    for (int k0 = 0; k0 < 64; k0 += 32) {
        short8 aF = *(const short8*)(&Af[(w * 16 + m) * APITCH + k0 + quad * 8]);
        short8 aB = *(const short8*)(&Ab[(w * 16 + m) * APITCH + k0 + quad * 8]);
        #pragma unroll
        for (int n = 0; n < 4; ++n) {
            short8 bF = *(const short8*)(&Bf[(n * 16 + m) * APITCH + k0 + quad * 8]);
            short8 bB = *(const short8*)(&Bb[(n * 16 + m) * APITCH + k0 + quad * 8]);
            accF[n] = __builtin_amdgcn_mfma_f32_16x16x32_bf16(aF, bF, accF[n], 0, 0, 0);
            accB[n] = __builtin_amdgcn_mfma_f32_16x16x32_bf16(aB, bB, accB[n], 0, 0, 0);
        }
    }

    // epilogue: plain stores of scaled messages (C/D layout col=m, row=quad*4+reg)
    int row_base = w * 16 + quad * 4;
    #pragma unroll
    for (int r = 0; r < 4; ++r) {
        int row = row_base + r;
        int e = eS[row];
        if (e >= 0) {
            float a = ivF[row], bsc = ivB[row];
            float* pf = msgF + (size_t)e * 64 + m;
            float* pb = msgB + (size_t)e * 64 + m;
            pf[ 0] = accF[0][r] * a;
            pf[16] = accF[1][r] * a;
            pf[32] = accF[2][r] * a;
            pf[48] = accF[3][r] * a;
            pb[ 0] = accB[0][r] * bsc;
            pb[16] = accB[1][r] * bsc;
            pb[32] = accB[2][r] * bsc;
            pb[48] = accB[3][r] * bsc;
        }
    }
}

// One wave per node: gather incoming messages and do one non-atomic out += .
// fwd messages for node n: edges with dst==n  (csrD, count cntb[n])
// bwd messages for node n: edges with src==n  (csrS, count cntf[n])
__global__ __launch_bounds__(256) void reduce_kernel(
        const int* __restrict__ cntf, const int* __restrict__ cntb,
        const int* __restrict__ curS, const int* __restrict__ curD,
        const int* __restrict__ csrS, const int* __restrict__ csrD,
        const float* __restrict__ msgF, const float* __restrict__ msgB,
        float* __restrict__ out, int N) {
    int tid = threadIdx.x, lane = tid & 63, w = tid >> 6;
    int n = blockIdx.x * 4 + w;
    if (n >= N) return;
    float acc = 0.f;
    int eD = curD[n], cD = cntb[n];
    for (int k = eD - cD; k < eD; ++k) {
        int e = csrD[k];
        acc += msgF[(size_t)e * 64 + lane];
    }
    int eS_ = curS[n], cS = cntf[n];
    for (int k = eS_ - cS; k < eS_; ++k) {
        int e = csrS[k];
        acc += msgB[(size_t)e * 64 + lane];
    }
    out[(size_t)n * 64 + lane] += acc;
}

extern "C" void kernel_launch(void* const* d_in, const int* in_sizes, int n_in,
                              void* d_out, int out_size, void* d_ws, size_t ws_size,
                              hipStream_t stream) {
    const float* x  = (const float*)d_in[0];
    const int*   ei = (const int*)  d_in[1];
    const int*   et = (const int*)  d_in[2];
    const float* wf = (const float*)d_in[3];
    const float* wb = (const float*)d_in[4];
    const float* lw = (const float*)d_in[5];
    const float* lb = (const float*)d_in[6];
    float* out = (float*)d_out;

    const int E = in_sizes[2];
    const int N = in_sizes[0] / 64;
    const int CAP = ((E + 63) >> 6) << 6;            // per-rel bucket capacity
    const int maxC = ((E + 63) >> 6) + NREL;         // 64-edge chunks upper bound

    char* p = (char*)d_ws;
    unsigned short* wtb = (unsigned short*)p;  p += (size_t)2 * NREL * 4096 * sizeof(unsigned short);
    unsigned short* xbf = (unsigned short*)p;  p += (size_t)N * 64 * sizeof(unsigned short);
    int*   cntf = (int*)p;                     p += (size_t)N * sizeof(int);
    int*   cntb = (int*)p;                     p += (size_t)N * sizeof(int);
    int*   fill = (int*)p;                     p += 32 * sizeof(int);      // 128 B
    int*   curS = (int*)p;                     p += (size_t)N * sizeof(int);
    int*   curD = (int*)p;                     p += (size_t)N * sizeof(int);
    float* invF = (float*)p;                   p += (size_t)N * sizeof(float);
    float* invB = (float*)p;                   p += (size_t)N * sizeof(float);
    int*   csrS = (int*)p;                     p += (size_t)E * sizeof(int);
    int*   csrD = (int*)p;                     p += (size_t)E * sizeof(int);
    p = (char*)(((size_t)p + 15) & ~(size_t)15);
    int4*  einfo = (int4*)p;                   p += (size_t)NREL * CAP * sizeof(int4);
    float* msgF = (float*)p;                   p += (size_t)E * 64 * sizeof(float);
    float* msgB = (float*)p;                   p += (size_t)E * 64 * sizeof(float);

    const int* srcp = ei;
    const int* dstp = ei + E;

    // zero cntf, cntb, fill (contiguous)
    hipMemsetAsync(cntf, 0, ((size_t)2 * N + NREL) * sizeof(int), stream);

    const int nCountB = (E + 255) / 256;
    const int nLinB   = (N + 31) / 32;
    setup_kernel<<<nCountB + 64 + nLinB, 256, 0, stream>>>(
        x, srcp, dstp, et, wf, wb, lw, lb, cntf, cntb, fill, wtb, xbf, einfo,
        out, E, N, nCountB, CAP);
    offsets_kernel<<<1, 1024, 0, stream>>>(cntf, cntb, curS, curD, invF, invB, N);
    csrfill_kernel<<<(E + 255) / 256, 256, 0, stream>>>(srcp, dstp, curS, curD, csrS, csrD, E);
    conv_mfma<<<maxC, 256, 0, stream>>>(xbf, invF, invB, fill, wtb, einfo, msgF, msgB, CAP);
    reduce_kernel<<<(N + 3) / 4, 256, 0, stream>>>(cntf, cntb, curS, curD, csrS, csrD,
                                                   msgF, msgB, out, N);
}

// Round 12
// 112.946 us; speedup vs baseline: 1.7095x; 1.7095x over previous
//
#include <hip/hip_runtime.h>

#define NREL 32

typedef short short8 __attribute__((ext_vector_type(8)));
typedef float f32x4 __attribute__((ext_vector_type(4)));

__device__ inline unsigned short f2bf(float f) {
    union { float f; unsigned u; } u; u.f = f;
    unsigned r = u.u + 0x7FFF + ((u.u >> 16) & 1);   // RNE
    return (unsigned short)(r >> 16);
}

// ---------------------------------------------------------------------------
// ws layout:
//   wtb  [2*32*4096] ushort  bf16 normalized tables, TRANSPOSED:
//                            wtb[(dir*32+r)*4096 + o*64 + i]
//   xbf  [N*64] ushort       bf16(x)
//   cntf [N] f32             # edges with src==n      (zeroed by memset)
//   cntb [N] f32             # edges with dst==n      (zeroed by memset)
//   fill [32] int            per-rel edge count / cursors (zeroed by memset)
//   einfo[32*CAP] int2       {src, dst} per edge, fixed-capacity rel buckets
// ---------------------------------------------------------------------------

// Fused independent setup (round-7 proven): count+scatter / norm / linear.
__global__ __launch_bounds__(256) void setup_kernel(
        const float* __restrict__ x,
        const int* __restrict__ src, const int* __restrict__ dst,
        const int* __restrict__ et,
        const float* __restrict__ wf, const float* __restrict__ wb,
        const float* __restrict__ lw, const float* __restrict__ lb,
        float* __restrict__ cntf, float* __restrict__ cntb,
        int* __restrict__ fill, unsigned short* __restrict__ wtb,
        unsigned short* __restrict__ xbf, int2* __restrict__ einfo,
        float* __restrict__ out, int E, int N, int nCountB, int CAP) {
    __shared__ float smem[4 * 8 * 64 + 8];
    int tid = threadIdx.x;
    int b = blockIdx.x;

    if (b < nCountB) {
        // ---- count + scatter role (block-aggregated cursors) ----
        int* lh = (int*)smem;          // [0..31] per-rel block count
        int* lbase = lh + NREL;        // [32..63] reserved global base
        if (tid < 2 * NREL) lh[tid] = 0;
        __syncthreads();
        int e = b * 256 + tid;
        int s = 0, d = 0, r = 0, my = 0;
        bool valid = (e < E);
        if (valid) {
            s = src[e]; d = dst[e]; r = et[e];
            atomicAdd(&cntf[s], 1.0f);
            atomicAdd(&cntb[d], 1.0f);
            my = atomicAdd(&lh[r], 1);
        }
        __syncthreads();
        if (tid < NREL && lh[tid]) lbase[tid] = atomicAdd(&fill[tid], lh[tid]);
        __syncthreads();
        if (valid) einfo[r * CAP + lbase[r] + my] = make_int2(s, d);
        return;
    }
    b -= nCountB;
    if (b < 64) {
        // ---- norm role: normalize fp32 table row, write bf16 transposed ----
        int rel = b & 31, tab = b >> 5;
        const float* s_ = (tab ? wb : wf) + rel * 4096;
        unsigned short* d_ = wtb + (size_t)b * 4096;
        float* part = smem;
        float ssum = 0.f;
        #pragma unroll
        for (int k = 0; k < 16; k += 4) {
            float4 v = *(const float4*)(s_ + tid * 16 + k);
            ssum += v.x * v.x + v.y * v.y + v.z * v.z + v.w * v.w;
        }
        #pragma unroll
        for (int off = 32; off >= 1; off >>= 1) ssum += __shfl_down(ssum, off, 64);
        if ((tid & 63) == 0) part[tid >> 6] = ssum;
        __syncthreads();
        if (tid == 0) part[4] = 1.0f / (sqrtf(part[0] + part[1] + part[2] + part[3]) + 0.01f);
        __syncthreads();
        float sc = part[4];
        int i = tid >> 2, o0 = (tid & 3) * 16;
        #pragma unroll
        for (int q = 0; q < 4; ++q) {
            float4 v = *(const float4*)(s_ + i * 64 + o0 + q * 4);
            d_[(o0 + q * 4 + 0) * 64 + i] = f2bf(v.x * sc);
            d_[(o0 + q * 4 + 1) * 64 + i] = f2bf(v.y * sc);
            d_[(o0 + q * 4 + 2) * 64 + i] = f2bf(v.z * sc);
            d_[(o0 + q * 4 + 3) * 64 + i] = f2bf(v.w * sc);
        }
        return;
    }
    b -= 64;
    // ---- linear + xbf role: 32 nodes/block ----
    {
        int lane = tid & 63, w = tid >> 6;
        int nodeBase = b * 32 + w * 8;
        float4 wrow[16];
        const float4* lwrow = (const float4*)(lw + lane * 64);
        #pragma unroll
        for (int g = 0; g < 16; ++g) wrow[g] = lwrow[g];
        float bias = lb[lane];
        float* xs = smem + w * 8 * 64;
        #pragma unroll
        for (int t = 0; t < 8; ++t) {
            int n = nodeBase + t;
            if (n < N) {
                float v = x[(size_t)n * 64 + lane];
                xs[t * 64 + lane] = v;
                xbf[(size_t)n * 64 + lane] = f2bf(v);
            }
        }
        __syncthreads();
        for (int t = 0; t < 8; ++t) {
            int n = nodeBase + t;
            if (n >= N) break;
            float acc = bias;
            const float4* xr = (const float4*)(xs + t * 64);
            #pragma unroll
            for (int g = 0; g < 16; ++g) {
                float4 xv = xr[g];
                acc = fmaf(xv.x, wrow[g].x, acc);
                acc = fmaf(xv.y, wrow[g].y, acc);
                acc = fmaf(xv.z, wrow[g].z, acc);
                acc = fmaf(xv.w, wrow[g].w, acc);
            }
            out[(size_t)n * 64 + lane] = acc;
        }
    }
}

// One block per (64-edge chunk) x (direction = blockIdx.y).
// LDS-FREE, BARRIER-FREE: A and B fragments load directly global->register
// (L2-resident); epilogue metadata moves lane-to-lane via shfl. Pad rows
// clamp their gather to slot 0 and are simply never written (MFMA C-rows
// are per-lane independent).
__global__ __launch_bounds__(256) void conv_mfma(
        const unsigned short* __restrict__ xbf,
        const float* __restrict__ cntf, const float* __restrict__ cntb,
        const int* __restrict__ fill,
        const unsigned short* __restrict__ wtb,
        const int2* __restrict__ einfo,
        float* __restrict__ out, int CAP) {
    int tid = threadIdx.x;
    int lane = tid & 63;

    // 64-edge chunk-count scan over fill[32]
    int fr = (lane < NREL) ? fill[lane] : 0;
    int ch = (fr + 63) >> 6;
    int s_scan = ch;
    #pragma unroll
    for (int off = 1; off < 32; off <<= 1) {
        int t = __shfl_up(s_scan, off, 64);
        if ((lane & 31) >= off) s_scan += t;
    }
    int chExcl = s_scan - ch;

    int c = blockIdx.x;
    unsigned long long mm = __ballot(lane < NREL && c >= chExcl && c < chExcl + ch);
    if (mm == 0) return;                    // past last chunk (uniform)
    int rel = __ffsll(mm) - 1;
    int lc = c - __shfl(chExcl, rel, 64);
    int frr = __shfl(fr, rel, 64);
    int pos = rel * CAP + lc * 64;
    int valid = frr - lc * 64;
    if (valid > 64) valid = 64;
    int dir = blockIdx.y;

    int w = tid >> 6, m = lane & 15, quad = lane >> 4;

    // this lane's A-row = w*16 + m (all 4 quads hold the same 16 rows,
    // different k-slices); pad rows clamp to slot 0
    int row = w * 16 + m;
    int2 v = einfo[pos + (row < valid ? row : 0)];
    int s_ = dir ? v.y : v.x;
    int d_ = dir ? v.x : v.y;
    float cv = dir ? cntb[s_] : cntf[s_];
    float inv = 1.0f / (cv + 1.0f);

    const unsigned short* xr = xbf + (size_t)s_ * 64 + quad * 8;
    short8 a0 = *(const short8*)(xr);
    short8 a1 = *(const short8*)(xr + 32);

    const unsigned short* bb = wtb + (size_t)((dir << 5) + rel) * 4096
                                   + m * 64 + quad * 8;
    f32x4 zero4 = {0.f, 0.f, 0.f, 0.f};
    f32x4 acc0 = zero4, acc1 = zero4, acc2 = zero4, acc3 = zero4;
    {
        short8 b0 = *(const short8*)(bb);
        short8 b1 = *(const short8*)(bb + 1024);
        short8 b2 = *(const short8*)(bb + 2048);
        short8 b3 = *(const short8*)(bb + 3072);
        acc0 = __builtin_amdgcn_mfma_f32_16x16x32_bf16(a0, b0, acc0, 0, 0, 0);
        acc1 = __builtin_amdgcn_mfma_f32_16x16x32_bf16(a0, b1, acc1, 0, 0, 0);
        acc2 = __builtin_amdgcn_mfma_f32_16x16x32_bf16(a0, b2, acc2, 0, 0, 0);
        acc3 = __builtin_amdgcn_mfma_f32_16x16x32_bf16(a0, b3, acc3, 0, 0, 0);
    }
    {
        short8 b0 = *(const short8*)(bb + 32);
        short8 b1 = *(const short8*)(bb + 1024 + 32);
        short8 b2 = *(const short8*)(bb + 2048 + 32);
        short8 b3 = *(const short8*)(bb + 3072 + 32);
        acc0 = __builtin_amdgcn_mfma_f32_16x16x32_bf16(a1, b0, acc0, 0, 0, 0);
        acc1 = __builtin_amdgcn_mfma_f32_16x16x32_bf16(a1, b1, acc1, 0, 0, 0);
        acc2 = __builtin_amdgcn_mfma_f32_16x16x32_bf16(a1, b2, acc2, 0, 0, 0);
        acc3 = __builtin_amdgcn_mfma_f32_16x16x32_bf16(a1, b3, acc3, 0, 0, 0);
    }

    // epilogue: C/D layout col=lane&15 (=m), row=quad*4+reg (m89-verified);
    // lane qq (quad 0) holds row qq's einfo/inv — fetch via shfl
    #pragma unroll
    for (int r = 0; r < 4; ++r) {
        int qq = quad * 4 + r;                 // row within this wave's 16
        int dd = __shfl(d_, qq, 64);
        float iv = __shfl(inv, qq, 64);
        if (w * 16 + qq < valid) {
            float* op = out + (size_t)dd * 64 + m;
            atomicAdd(op +  0, acc0[r] * iv);
            atomicAdd(op + 16, acc1[r] * iv);
            atomicAdd(op + 32, acc2[r] * iv);
            atomicAdd(op + 48, acc3[r] * iv);
        }
    }
}

extern "C" void kernel_launch(void* const* d_in, const int* in_sizes, int n_in,
                              void* d_out, int out_size, void* d_ws, size_t ws_size,
                              hipStream_t stream) {
    const float* x  = (const float*)d_in[0];
    const int*   ei = (const int*)  d_in[1];
    const int*   et = (const int*)  d_in[2];
    const float* wf = (const float*)d_in[3];
    const float* wb = (const float*)d_in[4];
    const float* lw = (const float*)d_in[5];
    const float* lb = (const float*)d_in[6];
    float* out = (float*)d_out;

    const int E = in_sizes[2];
    const int N = in_sizes[0] / 64;
    const int CAP = ((E + 63) >> 6) << 6;            // per-rel bucket capacity
    const int maxC = ((E + 63) >> 6) + NREL;         // 64-edge chunks upper bound

    char* p = (char*)d_ws;
    unsigned short* wtb = (unsigned short*)p;  p += (size_t)2 * NREL * 4096 * sizeof(unsigned short);
    unsigned short* xbf = (unsigned short*)p;  p += (size_t)N * 64 * sizeof(unsigned short);
    float* cntf = (float*)p;                   p += (size_t)N * sizeof(float);
    float* cntb = (float*)p;                   p += (size_t)N * sizeof(float);
    int*   fill = (int*)p;                     p += NREL * sizeof(int);
    int2*  einfo = (int2*)p;                   p += (size_t)NREL * CAP * sizeof(int2);

    const int* srcp = ei;
    const int* dstp = ei + E;

    // zero cntf, cntb, fill (contiguous)
    hipMemsetAsync(cntf, 0, ((size_t)2 * N + NREL) * sizeof(float), stream);

    const int nCountB = (E + 255) / 256;
    const int nLinB   = (N + 31) / 32;
    setup_kernel<<<nCountB + 64 + nLinB, 256, 0, stream>>>(
        x, srcp, dstp, et, wf, wb, lw, lb, cntf, cntb, fill, wtb, xbf, einfo,
        out, E, N, nCountB, CAP);
    dim3 cgrid(maxC, 2);
    conv_mfma<<<cgrid, 256, 0, stream>>>(xbf, cntf, cntb, fill, wtb, einfo, out, CAP);
}